// Round 12
// baseline (21.029 us; speedup 1.0000x reference)
//
#include <hip/hip_runtime.h>
#include <hip/hip_fp16.h>

#define LN_EPS 1e-5f

typedef float f2v __attribute__((ext_vector_type(2)));
typedef float f4v __attribute__((ext_vector_type(4)));

__device__ __forceinline__ unsigned pack2h(float a, float b) {
    return (unsigned)__half_as_ushort(__float2half_rn(a)) |
           ((unsigned)__half_as_ushort(__float2half_rn(b)) << 16);
}

// One block per sample n. 256 threads; thread t owns columns 2t, 2t+1.
// All global traffic float2 (512 B/wave/instr). FM in LDS as fp16 rows
// (one ds_read_b128 per gather); last Choquet step uses the constant
// FM[254] row in registers.
__global__ __launch_bounds__(256) void choquet_fused_kernel(
    const float* __restrict__ x,      // (N, 8, 512)
    const float* __restrict__ FM,     // (255, 8)
    const float* __restrict__ lnw,    // (8, 512)
    const float* __restrict__ lnb,    // (8, 512)
    const float* __restrict__ prelu,  // (1,)
    float* __restrict__ out)          // (N, 8, 512)
{
    constexpr int H = 8;
    __shared__ uint4 fm_h[255];       // fp16 rows, 16 B each, b128-aligned
    __shared__ float red[8];          // 4 waves x {sum, sumsq}

    const int n = blockIdx.x;
    const int t = threadIdx.x;

    // ---- streaming x loads: 8 float2 per thread ----
    const f2v* xp = (const f2v*)(x + (size_t)n * 4096) + t;
    f2v xv[8];
#pragma unroll
    for (int s = 0; s < 8; ++s)
        xv[s] = __builtin_nontemporal_load(xp + s * 256);

    // ---- stage FM as fp16 rows: thread t < 255 converts row t ----
    if (t < 255) {
        const f4v a = ((const f4v*)FM)[2 * t];
        const f4v b = ((const f4v*)FM)[2 * t + 1];
        uint4 pk;
        pk.x = pack2h(a.x, a.y);
        pk.y = pack2h(a.z, a.w);
        pk.z = pack2h(b.x, b.y);
        pk.w = pack2h(b.z, b.w);
        fm_h[t] = pk;
    }

    // last step's row is always FM[254] (mask == 255): f32, wave-uniform
    const f4v last0 = ((const f4v*)FM)[508];
    const f4v last1 = ((const f4v*)FM)[509];

    // ---- stable-equivalent descending sort of both columns ----
    // (value-only compare is exact: tied elements have zero diff and
    //  identical cumulative mask beyond the tie group)
    float vv[2][8];
    int   pp[2][8];                   // tracks 1 << original_index
#pragma unroll
    for (int s = 0; s < 8; ++s) {
        vv[0][s] = xv[s].x; vv[1][s] = xv[s].y;
        pp[0][s] = 1 << s;  pp[1][s] = 1 << s;
    }
#define CE(c, a, b)                                                           \
    {                                                                         \
        if (vv[c][a] < vv[c][b]) {                                            \
            float tv = vv[c][a]; vv[c][a] = vv[c][b]; vv[c][b] = tv;          \
            int   tp = pp[c][a]; pp[c][a] = pp[c][b]; pp[c][b] = tp;          \
        }                                                                     \
    }
#pragma unroll
    for (int c = 0; c < 2; ++c) {
        CE(c, 0, 1) CE(c, 2, 3) CE(c, 4, 5) CE(c, 6, 7)
        CE(c, 0, 2) CE(c, 1, 3) CE(c, 4, 6) CE(c, 5, 7)
        CE(c, 1, 2) CE(c, 5, 6) CE(c, 0, 4) CE(c, 3, 7)
        CE(c, 1, 5) CE(c, 2, 6)
        CE(c, 1, 4) CE(c, 3, 6)
        CE(c, 2, 4) CE(c, 3, 5)
        CE(c, 3, 4)
    }
#undef CE

    __syncthreads();   // FM staged

    // ---- Choquet accumulation, both columns interleaved ----
    float y[2][H];
#pragma unroll
    for (int c = 0; c < 2; ++c)
#pragma unroll
        for (int h = 0; h < H; ++h) y[c][h] = 0.f;

    int m0 = 0, m1 = 0;
#pragma unroll
    for (int s = 0; s < 7; ++s) {
        m0 |= pp[0][s]; m1 |= pp[1][s];
        const float d0 = vv[0][s] - vv[0][s + 1];
        const float d1 = vv[1][s] - vv[1][s + 1];
        const uint4 r0 = fm_h[m0 - 1];
        const uint4 r1 = fm_h[m1 - 1];
        const __half2* ha = (const __half2*)&r0;
        const __half2* hb = (const __half2*)&r1;
#pragma unroll
        for (int j = 0; j < 4; ++j) {
            const float2 qa = __half22float2(ha[j]);
            const float2 qb = __half22float2(hb[j]);
            y[0][2 * j]     += d0 * qa.x;
            y[0][2 * j + 1] += d0 * qa.y;
            y[1][2 * j]     += d1 * qb.x;
            y[1][2 * j + 1] += d1 * qb.y;
        }
    }
    // step 8: mask == 255 always -> constant f32 row, diff = sorted min
    {
        const float d0 = vv[0][7], d1 = vv[1][7];
        y[0][0] += d0 * last0.x; y[0][1] += d0 * last0.y;
        y[0][2] += d0 * last0.z; y[0][3] += d0 * last0.w;
        y[0][4] += d0 * last1.x; y[0][5] += d0 * last1.y;
        y[0][6] += d0 * last1.z; y[0][7] += d0 * last1.w;
        y[1][0] += d1 * last0.x; y[1][1] += d1 * last0.y;
        y[1][2] += d1 * last0.z; y[1][3] += d1 * last0.w;
        y[1][4] += d1 * last1.x; y[1][5] += d1 * last1.y;
        y[1][6] += d1 * last1.z; y[1][7] += d1 * last1.w;
    }

    // ---- issue LN param loads now; latency hides under the reduction ----
    f2v w2[H], b2[H];
#pragma unroll
    for (int h = 0; h < H; ++h) {
        w2[h] = ((const f2v*)lnw)[h * 256 + t];
        b2[h] = ((const f2v*)lnb)[h * 256 + t];
    }
    const float pw = prelu[0];

    // ---- block mean/var over 4096 values ----
    float s1 = 0.f, s2 = 0.f;
#pragma unroll
    for (int c = 0; c < 2; ++c)
#pragma unroll
        for (int h = 0; h < H; ++h) { s1 += y[c][h]; s2 += y[c][h] * y[c][h]; }
#pragma unroll
    for (int off = 32; off > 0; off >>= 1) {
        s1 += __shfl_xor(s1, off);
        s2 += __shfl_xor(s2, off);
    }
    const int wid = t >> 6;
    if ((t & 63) == 0) { red[wid * 2] = s1; red[wid * 2 + 1] = s2; }
    __syncthreads();

    float t1 = 0.f, t2 = 0.f;
#pragma unroll
    for (int wv = 0; wv < 4; ++wv) { t1 += red[wv * 2]; t2 += red[wv * 2 + 1]; }
    const float mean = t1 * (1.0f / 4096.0f);
    float var = t2 * (1.0f / 4096.0f) - mean * mean;
    var = var < 0.f ? 0.f : var;
    const float rstd = rsqrtf(var + LN_EPS);

    f2v* op = (f2v*)(out + (size_t)n * 4096) + t;
#pragma unroll
    for (int h = 0; h < H; ++h) {
        float v0 = (y[0][h] - mean) * rstd * w2[h].x + b2[h].x;
        float v1 = (y[1][h] - mean) * rstd * w2[h].y + b2[h].y;
        v0 = v0 > 0.f ? v0 : pw * v0;
        v1 = v1 > 0.f ? v1 : pw * v1;
        f2v o; o.x = v0; o.y = v1;
        __builtin_nontemporal_store(o, op + h * 256);
    }
}

extern "C" void kernel_launch(void* const* d_in, const int* in_sizes, int n_in,
                              void* d_out, int out_size, void* d_ws, size_t ws_size,
                              hipStream_t stream) {
    const float* x     = (const float*)d_in[0];
    const float* FM    = (const float*)d_in[1];
    const float* lnw   = (const float*)d_in[2];
    const float* lnb   = (const float*)d_in[3];
    const float* prelu = (const float*)d_in[4];
    float* out = (float*)d_out;

    const int N = in_sizes[0] / (8 * 512);
    choquet_fused_kernel<<<N, 256, 0, stream>>>(x, FM, lnw, lnb, prelu, out);
}